// Round 6
// baseline (546.008 us; speedup 1.0000x reference)
//
#include <hip/hip_runtime.h>

typedef __bf16 bf16x8 __attribute__((ext_vector_type(8)));
typedef float f32x16 __attribute__((ext_vector_type(16)));
typedef unsigned int u32x4 __attribute__((ext_vector_type(4)));

#define NGROUP 8
#define DMODEL 256
#define DFF    1024
#define TTOT   131072
#define TGRP   (TTOT / NGROUP)   // 16384
#define MTILE  256               // tokens per block (4 waves x 64)
#define NCHUNK 32                // f-chunks of 32 (DFF/32)
// Block = 4 waves (256 thr), each wave owns 64 tokens (two 32-token blocks).
// Every LDS weight-fragment read now feeds TWO MFMAs (one per token block):
// per-CU LDS ops/chunk drop 432 -> 240 while MFMA work is unchanged -- the
// LDS pipe (the measured bottleneck across rounds 2-5) is no longer pinned.
// Cost: acc 256 + xf 128 regs -> ~1 wave/SIMD (full 512-reg budget).
// LDS map (144 KB): THREE 48KB chunk buffers, staged 2 chunks ahead with
// counted vmcnt(12) (never drains in-loop).
//   buf s at u32x4 offset s*3072:
//     [   0, 16K)  gate A-frags [ks(16)][lane(64)] x 16B
//     [ 16K, 32K)  up   A-frags
//     [ 32K, 48K)  down B-frags [fi(16)][lane(64)] x 16B (k-permuted at prep)

__device__ __forceinline__ unsigned int f2bf(float f) {
    unsigned int x = __builtin_bit_cast(unsigned int, f);
    return (x + 0x7fffu + ((x >> 16) & 1u)) >> 16;   // RNE
}
__device__ __forceinline__ unsigned int pack2(float lo, float hi) {
    return f2bf(lo) | (f2bf(hi) << 16);
}
__device__ __forceinline__ unsigned int cvtpk(float lo, float hi) {
    unsigned int r;
    asm("v_cvt_pk_bf16_f32 %0, %1, %2" : "=v"(r) : "v"(lo), "v"(hi));  // RNE
    return r;
}

__device__ __forceinline__ void g2l(const void* g, void* l) {
    __builtin_amdgcn_global_load_lds(
        (const __attribute__((address_space(1))) unsigned int*)g,
        (__attribute__((address_space(3))) unsigned int*)l, 16, 0, 0);
}

// ---------------- prep: all weights -> per-(group,chunk) 48KB frag blocks ----------------
//   fid 0..15  : gate A-frag, ks=fid      W[d=ks*16+q*8+j][f=c*32+l31]
//   fid 16..31 : up   A-frag, ks=fid-16
//   fid 32..47 : down B-frag, ks2=(fid-32)>>3, nb=(fid-32)&7
//     k-axis PERMUTED to match packed-accumulator A-frags:
//     B[k=q*8+j] = Wd[F = c*32 + ks2*16 + q*4 + (j&3) + 8*(j>>2)][col=nb*32+l31]
__global__ void k_prep_w(const float* __restrict__ wg, const float* __restrict__ wu,
                         const float* __restrict__ wd, u32x4* __restrict__ out) {
    int t = blockIdx.x * 256 + threadIdx.x;   // 786432 total
    int lane = t & 63;
    int q = lane >> 5, l31 = lane & 31;
    int fg = t >> 6;
    int fid = fg % 48;
    int gc  = fg / 48;
    int c = gc & 31, g = gc >> 5;
    u32x4 v;
    if (fid < 32) {
        const float* w = (fid < 16) ? wg : wu;
        int ks = fid & 15;
        const float* src = w + (size_t)(g * 256 + ks * 16 + q * 8) * 1024 + c * 32 + l31;
        v = u32x4{ pack2(src[0],        src[1024]),
                   pack2(src[2 * 1024], src[3 * 1024]),
                   pack2(src[4 * 1024], src[5 * 1024]),
                   pack2(src[6 * 1024], src[7 * 1024]) };
    } else {
        int idx = fid - 32;
        int ks2 = idx >> 3, nb = idx & 7;
        // rows f = base + {0,1,2,3, 8,9,10,11}  (permuted k-axis)
        const float* src = wd + (size_t)(g * 1024 + c * 32 + ks2 * 16 + q * 4) * 256 + nb * 32 + l31;
        v = u32x4{ pack2(src[0 * 256],  src[1 * 256]),
                   pack2(src[2 * 256],  src[3 * 256]),
                   pack2(src[8 * 256],  src[9 * 256]),
                   pack2(src[10 * 256], src[11 * 256]) };
    }
    out[t] = v;
}

#define MFMA(A, B, C) __builtin_amdgcn_mfma_f32_32x32x16_bf16( \
        __builtin_bit_cast(bf16x8, A), __builtin_bit_cast(bf16x8, B), C, 0, 0, 0)

// ---------------- main fused grouped-GLU ----------------
__global__ __launch_bounds__(256, 1)
void k_glu(const float* __restrict__ x,      // fp32 x row-major [T][256]
           const u32x4* __restrict__ wcomb,  // [g][c][48 frag-groups][64 lanes]
           float* __restrict__ y) {
    __shared__ u32x4 smem[9216];   // 144 KB: three 48KB buffers

    const int tid  = threadIdx.x;
    const int lane = tid & 63;
    const int w    = tid >> 6;      // wave 0..3, owns tokens w*64 .. w*64+63
    const int q    = lane >> 5;
    const int l31  = lane & 31;

    // XCD swizzle: group = blockIdx & 7 so each XCD's L2 holds one group's weights
    const int g    = blockIdx.x & 7;
    const int m0   = g * TGRP + (blockIdx.x >> 3) * MTILE;
    const int tok0 = m0 + w * 64 + l31;        // token block 0
    const int tok1 = tok0 + 32;                // token block 1

    const u32x4* wcg = wcomb + (size_t)(g * 32) * 3072;

    // ---- prologue: stage chunk0 -> buf0, chunk1 -> buf1 (12 g2l each per wave)
    #pragma unroll
    for (int i = 0; i < 12; ++i) {
        int off = i * 256 + w * 64;   // u32x4 index, wave-uniform LDS dest
        g2l(wcg + off + lane, smem + off);
    }
    #pragma unroll
    for (int i = 0; i < 12; ++i) {
        int off = i * 256 + w * 64;
        g2l(wcg + 3072 + off + lane, smem + 3072 + off);
    }
    // x -> bf16 B-frags for both token blocks (register-resident)
    u32x4 xf0[16], xf1[16];
    {
        const float* xr0 = x + (size_t)tok0 * DMODEL + q * 8;
        const float* xr1 = x + (size_t)tok1 * DMODEL + q * 8;
        #pragma unroll
        for (int ks = 0; ks < 16; ++ks) {
            float4 a = *(const float4*)(xr0 + ks * 16);
            float4 b = *(const float4*)(xr0 + ks * 16 + 4);
            xf0[ks] = u32x4{ cvtpk(a.x, a.y), cvtpk(a.z, a.w),
                             cvtpk(b.x, b.y), cvtpk(b.z, b.w) };
            float4 cfour = *(const float4*)(xr1 + ks * 16);
            float4 d = *(const float4*)(xr1 + ks * 16 + 4);
            xf1[ks] = u32x4{ cvtpk(cfour.x, cfour.y), cvtpk(cfour.z, cfour.w),
                             cvtpk(d.x, d.y), cvtpk(d.z, d.w) };
        }
    }

    f32x16 acc0[8], acc1[8];
    #pragma unroll
    for (int nb = 0; nb < 8; ++nb)
        #pragma unroll
        for (int i = 0; i < 16; ++i) { acc0[nb][i] = 0.0f; acc1[nb][i] = 0.0f; }

    asm volatile("s_waitcnt vmcnt(0)" ::: "memory");   // chunks 0/1 staged, x loaded
    __builtin_amdgcn_s_barrier();
    asm volatile("" ::: "memory");

    int bc = 0;   // buffer slot of current chunk (c % 3)
    for (int c = 0; c < NCHUNK; ++c) {
        const u32x4* sbc = smem + bc * 3072;

        if (c > 0) {
            // chunk-c staging (issued at iter c-2 or prologue) must be done;
            // newest 12 outstanding ops are the (c+1)-staging -- never wait on them
            if (c <= NCHUNK - 2) {
                asm volatile("s_waitcnt vmcnt(12)" ::: "memory");
            } else {
                asm volatile("s_waitcnt vmcnt(0)" ::: "memory");
            }
            __builtin_amdgcn_s_barrier();   // buf (c+2)%3's readers (iter c-1) done
            asm volatile("" ::: "memory");
        }

        // ---- stage chunk c+2 into buf (c+2)%3 (12 g2l per wave)
        if (c + 2 < NCHUNK) {
            const int bn = (bc + 2 >= 3) ? bc - 1 : bc + 2;
            u32x4* db = smem + bn * 3072;
            const u32x4* gsrc = wcg + (size_t)(c + 2) * 3072;
            #pragma unroll
            for (int i = 0; i < 12; ++i) {
                int off = i * 256 + w * 64;
                g2l(gsrc + off + lane, db + off);
            }
        }

        // ---- GEMM1: each weight frag read feeds BOTH token blocks (1 read : 2 MFMA)
        f32x16 zg0, zu0, zg1, zu1;
        #pragma unroll
        for (int i = 0; i < 16; ++i) { zg0[i] = 0.0f; zu0[i] = 0.0f; zg1[i] = 0.0f; zu1[i] = 0.0f; }
        __builtin_amdgcn_s_setprio(1);
        #pragma unroll
        for (int ks = 0; ks < 16; ++ks) {
            const u32x4 a1 = sbc[ks * 64 + lane];          // gate
            const u32x4 a2 = sbc[1024 + ks * 64 + lane];   // up
            zg0 = MFMA(a1, xf0[ks], zg0);
            zg1 = MFMA(a1, xf1[ks], zg1);
            zu0 = MFMA(a2, xf0[ks], zu0);
            zu1 = MFMA(a2, xf1[ks], zu1);
        }
        __builtin_amdgcn_s_setprio(0);

        // ---- act for both token blocks -> A-frags (in-register, k-permuted layout)
        u32x4 A00, A01, A10, A11;
        {
            float hv[16];
            #pragma unroll
            for (int i = 0; i < 16; ++i) {
                const float gv = zg0[i];
                const float s  = __builtin_amdgcn_rcpf(1.0f + __expf(-gv));
                hv[i] = gv * s * zu0[i];
            }
            A00 = u32x4{ cvtpk(hv[0], hv[1]),   cvtpk(hv[2], hv[3]),
                         cvtpk(hv[4], hv[5]),   cvtpk(hv[6], hv[7]) };
            A01 = u32x4{ cvtpk(hv[8], hv[9]),   cvtpk(hv[10], hv[11]),
                         cvtpk(hv[12], hv[13]), cvtpk(hv[14], hv[15]) };
            #pragma unroll
            for (int i = 0; i < 16; ++i) {
                const float gv = zg1[i];
                const float s  = __builtin_amdgcn_rcpf(1.0f + __expf(-gv));
                hv[i] = gv * s * zu1[i];
            }
            A10 = u32x4{ cvtpk(hv[0], hv[1]),   cvtpk(hv[2], hv[3]),
                         cvtpk(hv[4], hv[5]),   cvtpk(hv[6], hv[7]) };
            A11 = u32x4{ cvtpk(hv[8], hv[9]),   cvtpk(hv[10], hv[11]),
                         cvtpk(hv[12], hv[13]), cvtpk(hv[14], hv[15]) };
        }

        // ---- GEMM2: 1 bd read : 2 MFMAs (both token blocks)
        __builtin_amdgcn_s_setprio(1);
        #pragma unroll
        for (int fi = 0; fi < 8; ++fi) {
            const u32x4 bd = sbc[2048 + fi * 64 + lane];
            acc0[fi] = MFMA(A00, bd, acc0[fi]);
            acc1[fi] = MFMA(A10, bd, acc1[fi]);
        }
        #pragma unroll
        for (int fi = 0; fi < 8; ++fi) {
            const u32x4 bd = sbc[2048 + (8 + fi) * 64 + lane];
            acc0[fi] = MFMA(A01, bd, acc0[fi]);
            acc1[fi] = MFMA(A11, bd, acc1[fi]);
        }
        __builtin_amdgcn_s_setprio(0);

        bc = (bc == 2) ? 0 : bc + 1;
    }

    // epilogue: C layout -> y fp32 (two 32-token blocks per wave)
    {
        float* yp = y + (size_t)(m0 + w * 64) * DMODEL;
        #pragma unroll
        for (int nb = 0; nb < 8; ++nb) {
            const int col = nb * 32 + l31;
            #pragma unroll
            for (int r = 0; r < 16; ++r) {
                const int row = (r & 3) + (r >> 2) * 8 + q * 4;
                yp[(size_t)row * DMODEL + col] = acc0[nb][r];
            }
        }
        float* yq = yp + 32 * DMODEL;
        #pragma unroll
        for (int nb = 0; nb < 8; ++nb) {
            const int col = nb * 32 + l31;
            #pragma unroll
            for (int r = 0; r < 16; ++r) {
                const int row = (r & 3) + (r >> 2) * 8 + q * 4;
                yq[(size_t)row * DMODEL + col] = acc1[nb][r];
            }
        }
    }
}

extern "C" void kernel_launch(void* const* d_in, const int* in_sizes, int n_in,
                              void* d_out, int out_size, void* d_ws, size_t ws_size,
                              hipStream_t stream) {
    const float* x  = (const float*)d_in[0];
    const float* wg = (const float*)d_in[1];
    const float* wu = (const float*)d_in[2];
    const float* wd = (const float*)d_in[3];
    float* y = (float*)d_out;

    // ws: wcomb only (12.6 MB); x is consumed fp32 directly by k_glu
    u32x4* wcomb = (u32x4*)d_ws;   // 8*32*48*64 = 786432 u32x4

    k_prep_w<<<dim3(3072), dim3(256), 0, stream>>>(wg, wu, wd, wcomb);
    k_glu<<<dim3(512), dim3(256), 0, stream>>>(x, wcomb, y);
}